// Round 2
// baseline (530.692 us; speedup 1.0000x reference)
//
#include <hip/hip_runtime.h>

// Problem: out[b,k,n,m] = clip(exp(-0.1 * sqrt(max(|An|^2 - 2 An.Am + |Am|^2, 1e-6))), 0, 1)
// with A = x * msk, x: (8,64,512,16) fp32, msk: (8,64,512,1) fp32.
// Output: (8,64,512,512,1) fp32 = 512 MiB -> HBM-write-bound (~85 us floor at 6.3 TB/s).
//
// Strategy: one block per 128x128 tile of a (b,k) slice. Stage node tiles to LDS
// transposed [f][node] so fragment reads are contiguous ds_read_b128. Each thread
// owns an 8x8 register tile (rows/cols split as base + {0,64} so LDS read starts
// are stride-4 across tx -> <=2-way bank aliasing, which is free on gfx950).
// Epilogue fused in registers; output streamed with nontemporal f32x4 stores.
// NOTE: use clang ext_vector_type for stores — __builtin_nontemporal_store
// rejects HIP_vector_type<float,4>.

typedef float f32x4 __attribute__((ext_vector_type(4)));

#define NEG_DIST_LOG2E (-0.14426950408889634f)  // -0.1 * log2(e)
#define EPS_F 1e-6f

__global__ __launch_bounds__(256) void node_pair_gaussian_kernel(
    const float* __restrict__ x,    // (512 slices, 512 nodes, 16 f)
    const float* __restrict__ msk,  // (512 slices, 512 nodes)
    float* __restrict__ out)        // (512 slices, 512, 512)
{
    __shared__ __align__(16) float lds_n[16][128];
    __shared__ __align__(16) float lds_m[16][128];
    __shared__ __align__(16) float na_n[128];
    __shared__ __align__(16) float na_m[128];

    const int tid   = threadIdx.x;          // 0..255
    const int tile  = blockIdx.x;           // 0..15
    const int slice = blockIdx.y;           // 0..511  (= b*64 + k)
    const int n0 = (tile >> 2) << 7;        // row tile base
    const int m0 = (tile & 3) << 7;         // col tile base

    const float* xs = x   + (size_t)slice * (512 * 16);
    const float* ms = msk + (size_t)slice * 512;

    // ---- Stage both 128x16 tiles into LDS, transposed to [f][node], masked ----
    #pragma unroll
    for (int it = 0; it < 2; ++it) {
        const int task = tid + it * 256;    // 0..511 = 128 nodes x 4 f4-chunks
        const int node = task & 127;
        const int f4   = task >> 7;         // 0..3
        {
            const f32x4 v = *(const f32x4*)(xs + (size_t)(n0 + node) * 16 + f4 * 4);
            const float mm = ms[n0 + node];
            lds_n[f4 * 4 + 0][node] = v.x * mm;
            lds_n[f4 * 4 + 1][node] = v.y * mm;
            lds_n[f4 * 4 + 2][node] = v.z * mm;
            lds_n[f4 * 4 + 3][node] = v.w * mm;
        }
        {
            const f32x4 v = *(const f32x4*)(xs + (size_t)(m0 + node) * 16 + f4 * 4);
            const float mm = ms[m0 + node];
            lds_m[f4 * 4 + 0][node] = v.x * mm;
            lds_m[f4 * 4 + 1][node] = v.y * mm;
            lds_m[f4 * 4 + 2][node] = v.z * mm;
            lds_m[f4 * 4 + 3][node] = v.w * mm;
        }
    }
    __syncthreads();

    // ---- Cooperative squared-norm precompute ----
    {
        const int node = tid & 127;
        float s = 0.0f;
        if (tid < 128) {
            #pragma unroll
            for (int f = 0; f < 16; ++f) s = fmaf(lds_m[f][node], lds_m[f][node], s);
            na_m[node] = s;
        } else {
            #pragma unroll
            for (int f = 0; f < 16; ++f) s = fmaf(lds_n[f][node], lds_n[f][node], s);
            na_n[node] = s;
        }
    }
    __syncthreads();

    // ---- 8x8 register-tile Gram accumulation ----
    const int tx = tid & 15;    // col group
    const int ty = tid >> 4;    // row group

    float acc[8][8];
    #pragma unroll
    for (int i = 0; i < 8; ++i)
        #pragma unroll
        for (int j = 0; j < 8; ++j) acc[i][j] = 0.0f;

    #pragma unroll
    for (int f = 0; f < 16; ++f) {
        const f32x4 a0 = *(const f32x4*)&lds_n[f][ty * 4];
        const f32x4 a1 = *(const f32x4*)&lds_n[f][64 + ty * 4];
        const f32x4 b0 = *(const f32x4*)&lds_m[f][tx * 4];
        const f32x4 b1 = *(const f32x4*)&lds_m[f][64 + tx * 4];
        const float an[8] = {a0.x, a0.y, a0.z, a0.w, a1.x, a1.y, a1.z, a1.w};
        const float am[8] = {b0.x, b0.y, b0.z, b0.w, b1.x, b1.y, b1.z, b1.w};
        #pragma unroll
        for (int i = 0; i < 8; ++i)
            #pragma unroll
            for (int j = 0; j < 8; ++j)
                acc[i][j] = fmaf(an[i], am[j], acc[i][j]);
    }

    const f32x4 nn0 = *(const f32x4*)&na_n[ty * 4];
    const f32x4 nn1 = *(const f32x4*)&na_n[64 + ty * 4];
    const f32x4 nm0 = *(const f32x4*)&na_m[tx * 4];
    const f32x4 nm1 = *(const f32x4*)&na_m[64 + tx * 4];
    const float nn[8] = {nn0.x, nn0.y, nn0.z, nn0.w, nn1.x, nn1.y, nn1.z, nn1.w};
    const float nm[8] = {nm0.x, nm0.y, nm0.z, nm0.w, nm1.x, nm1.y, nm1.z, nm1.w};

    float* outs = out + (size_t)slice * (512 * 512) + (size_t)n0 * 512 + m0;

    // ---- Fused epilogue + streaming stores ----
    #pragma unroll
    for (int i = 0; i < 8; ++i) {
        const int row = (i < 4) ? (ty * 4 + i) : (64 + ty * 4 + (i - 4));
        float r[8];
        #pragma unroll
        for (int j = 0; j < 8; ++j) {
            float s = nn[i] + nm[j] - 2.0f * acc[i][j];
            s = fmaxf(s, EPS_F);
            const float d = __builtin_amdgcn_sqrtf(s);
            const float e = __builtin_amdgcn_exp2f(d * NEG_DIST_LOG2E);
            r[j] = fminf(e, 1.0f);   // CLIP_LOW=0 is implied: e > 0 always
        }
        f32x4 w0 = {r[0], r[1], r[2], r[3]};
        f32x4 w1 = {r[4], r[5], r[6], r[7]};
        __builtin_nontemporal_store(w0, (f32x4*)(outs + (size_t)row * 512 + tx * 4));
        __builtin_nontemporal_store(w1, (f32x4*)(outs + (size_t)row * 512 + 64 + tx * 4));
    }
}

extern "C" void kernel_launch(void* const* d_in, const int* in_sizes, int n_in,
                              void* d_out, int out_size, void* d_ws, size_t ws_size,
                              hipStream_t stream) {
    const float* x   = (const float*)d_in[0];   // (8,64,512,16) fp32
    const float* msk = (const float*)d_in[1];   // (8,64,512,1)  fp32
    float* out = (float*)d_out;                 // (8,64,512,512,1) fp32

    dim3 grid(16, 512);   // 16 tiles of 128x128 per slice, 512 slices
    node_pair_gaussian_kernel<<<grid, 256, 0, stream>>>(x, msk, out);
}